// Round 4
// baseline (5076.767 us; speedup 1.0000x reference)
//
#include <hip/hip_runtime.h>
#include <cstdint>
#include <cstddef>

// Problem dims (fixed by setup_inputs)
#define BB    2048
#define SS    256
#define HH    256
#define AA    2
#define TT    50
#define NB    4      // batch rows per block
#define NBLK  512    // blocks -> 2 per CU
#define NTHR  256
#define K4PAD 1088           // floats per k4 tile (1024 + 64 pad -> 4352B stride, no L1 aliasing)
#define WLAYER (64 * K4PAD)  // 69632 floats per layer

struct Params {
  const float* x;
  const float* fu[3]; const float* fv[3]; const float* fs[3];
  const float* f4u; const float* f4v; const float* f4s;
  const float* W[3]; const float* bs[3];
  const float* W4; const float* b4;
  float* out;
  float* wt3;         // [3][64 k4][256 h *4 + pad]
  float* partials;    // [2 slots][4 layers][6 stats][NBLK]
  unsigned* bar;      // [ctr, gen]
  float* P1;          // [TT][BB][HH]  layer-1 pre-activations (no bias)
  int use_p1;
};

__device__ __forceinline__ void pstore(float* p, float v) {
  __hip_atomic_store(p, v, __ATOMIC_RELAXED, __HIP_MEMORY_SCOPE_AGENT);
}
__device__ __forceinline__ float pload(const float* p) {
  return __hip_atomic_load(p, __ATOMIC_RELAXED, __HIP_MEMORY_SCOPE_AGENT);
}

__device__ __forceinline__ void bar_arrive(unsigned* bar, int b) {
  __syncthreads();
  if (threadIdx.x == 0) {
    unsigned old = __hip_atomic_fetch_add(bar, 1u, __ATOMIC_ACQ_REL, __HIP_MEMORY_SCOPE_AGENT);
    if (old == (unsigned)((b + 1) * NBLK - 1))
      __hip_atomic_store(bar + 1, (unsigned)(b + 1), __ATOMIC_RELEASE, __HIP_MEMORY_SCOPE_AGENT);
  }
}
__device__ __forceinline__ void bar_wait(unsigned* bar, int b) {
  if (threadIdx.x == 0) {
    while ((int)__hip_atomic_load(bar + 1, __ATOMIC_ACQUIRE, __HIP_MEMORY_SCOPE_AGENT) < b + 1)
      __builtin_amdgcn_s_sleep(2);
  }
  __syncthreads();
}

#define FMA4(ACC, IV, WS)                 \
  ACC[0] = fmaf((IV).x, (WS), ACC[0]);    \
  ACC[1] = fmaf((IV).y, (WS), ACC[1]);    \
  ACC[2] = fmaf((IV).z, (WS), ACC[2]);    \
  ACC[3] = fmaf((IV).w, (WS), ACC[3]);

__global__ __launch_bounds__(NTHR, 2)
void snn_kernel(Params p) {
#pragma clang fp contract(off)
  const int tid = threadIdx.x;
  const int blk = blockIdx.x;
  const int gtid = blk * NTHR + tid;
  const int B0 = blk * NB;
  const int h0 = tid;

  __shared__ __align__(16) float smem[SS * 44];   // phase0 xs; aliases below
  float* in_lds = smem;              // [256][NB] spikes / gemm input
  float* x_lds  = smem + SS * NB;    // [256][NB] fallback x staging
  __shared__ float wred[4][6];
  __shared__ float scal[4][2];
  __shared__ float l4u[8], l4v[8], l4s[8], l4t[8], l4acc[8], l4vn[8], l4vth[8];

  // ---- prologue: W -> padded k-tiled layout (blocks 0..63 write) ----
  if (gtid < 16384) {
    const int h = tid, k4 = blk;   // blk < 64
    #pragma unroll
    for (int l = 0; l < 3; ++l) {
      float4 w = *reinterpret_cast<const float4*>(p.W[l] + (size_t)h * 256 + k4 * 4);
      *reinterpret_cast<float4*>(p.wt3 + (size_t)l * WLAYER + (size_t)k4 * K4PAD + h * 4) = w;
    }
  }
  bar_arrive(p.bar, 0);
  bar_wait(p.bar, 0);   // wt3 visible everywhere

  // ---- phase 0: P1[t][b][h] = x_t @ W1.T (no bias), 5 tiles of 10 t ----
  if (p.use_p1) {
    float* xs = smem;   // [256][44]
    const float* wpf = p.wt3 + (h0 << 2);
    #pragma unroll 1
    for (int tt = 0; tt < 5; ++tt) {
      __syncthreads();
      {
        const int s0 = tid;
        #pragma unroll
        for (int b = 0; b < 4; ++b) {
          const float* src = p.x + ((size_t)(B0 + b) * SS + s0) * TT + tt * 10;
          #pragma unroll
          for (int tq = 0; tq < 10; ++tq)
            xs[s0 * 44 + b * 10 + tq] = src[tq];
        }
      }
      __syncthreads();
      float acc[4][10];
      #pragma unroll
      for (int b = 0; b < 4; ++b)
        #pragma unroll
        for (int tq = 0; tq < 10; ++tq) acc[b][tq] = 0.0f;

      float4 wc = *reinterpret_cast<const float4*>(wpf);
      #pragma unroll 1
      for (int s4 = 0; s4 < 64; ++s4) {
        float4 wn = *reinterpret_cast<const float4*>(wpf + ((s4 + 1) & 63) * K4PAD);
        #pragma unroll
        for (int ss = 0; ss < 4; ++ss) {
          const float4* xrow = reinterpret_cast<const float4*>(xs + (s4 * 4 + ss) * 44);
          float xrf[40];
          #pragma unroll
          for (int q = 0; q < 10; ++q)
            *reinterpret_cast<float4*>(&xrf[q * 4]) = xrow[q];
          const float wss = (ss == 0) ? wc.x : (ss == 1) ? wc.y : (ss == 2) ? wc.z : wc.w;
          #pragma unroll
          for (int b = 0; b < 4; ++b)
            #pragma unroll
            for (int tq = 0; tq < 10; ++tq)
              acc[b][tq] = fmaf(xrf[b * 10 + tq], wss, acc[b][tq]);
        }
        wc = wn;
      }
      #pragma unroll
      for (int b = 0; b < 4; ++b)
        #pragma unroll
        for (int tq = 0; tq < 10; ++tq)
          p.P1[((size_t)(tt * 10 + tq) * BB + B0 + b) * HH + h0] = acc[b][tq];
    }
    __syncthreads();   // xs reuse as in_lds/x_lds safe; P1 stores drained at barrier
  }

  // ---- load recurrent state ----
  float u[3][NB], v[3][NB], s[3][NB], tp[3][NB];
  #pragma unroll
  for (int l = 0; l < 3; ++l)
    #pragma unroll
    for (int j = 0; j < NB; ++j) {
      size_t idx = (size_t)(B0 + j) * HH + h0;
      u[l][j] = p.fu[l][idx];
      v[l][j] = p.fv[l][idx];
      s[l][j] = p.fs[l][idx];
      tp[l][j] = 0.5f;
    }
  if (tid < 8) {
    int j = tid >> 1, a = tid & 1;
    size_t idx = (size_t)(B0 + j) * AA + a;
    l4u[tid] = p.f4u[idx]; l4v[tid] = p.f4v[idx]; l4s[tid] = p.f4s[idx];
    l4t[tid] = 0.5f; l4acc[tid] = 0.0f;
  }
  const float bL[3] = { p.bs[0][h0], p.bs[1][h0], p.bs[2][h0] };

  // GEMM for layers (k ascending, per-acc fmaf chain identical to rounds 1-3)
  auto gemm = [&](const float* __restrict__ wb, const float* __restrict__ src,
                  float acc[NB]) {
    acc[0] = acc[1] = acc[2] = acc[3] = 0.0f;
    const float* wpf = wb + (h0 << 2);
    float4 w0 = *reinterpret_cast<const float4*>(wpf + 0 * K4PAD);
    float4 w1 = *reinterpret_cast<const float4*>(wpf + 1 * K4PAD);
    float4 w2 = *reinterpret_cast<const float4*>(wpf + 2 * K4PAD);
    float4 w3 = *reinterpret_cast<const float4*>(wpf + 3 * K4PAD);
    #pragma unroll 1
    for (int k4 = 0; k4 < 64; k4 += 4) {
      const int nk = (k4 + 4 < 64) ? (k4 + 4) : 0;   // dummy re-read on last iter
      float4 n0 = *reinterpret_cast<const float4*>(wpf + (nk + 0) * K4PAD);
      float4 n1 = *reinterpret_cast<const float4*>(wpf + (nk + 1) * K4PAD);
      float4 n2 = *reinterpret_cast<const float4*>(wpf + (nk + 2) * K4PAD);
      float4 n3 = *reinterpret_cast<const float4*>(wpf + (nk + 3) * K4PAD);
      #pragma unroll
      for (int q = 0; q < 4; ++q) {
        const float4 w = (q == 0) ? w0 : (q == 1) ? w1 : (q == 2) ? w2 : w3;
        const float* srow = src + (size_t)(k4 + q) * 4 * NB;
        float4 i0 = *reinterpret_cast<const float4*>(srow + 0);
        float4 i1 = *reinterpret_cast<const float4*>(srow + 4);
        float4 i2 = *reinterpret_cast<const float4*>(srow + 8);
        float4 i3 = *reinterpret_cast<const float4*>(srow + 12);
        FMA4(acc, i0, w.x);
        FMA4(acc, i1, w.y);
        FMA4(acc, i2, w.z);
        FMA4(acc, i3, w.w);
      }
      w0 = n0; w1 = n1; w2 = n2; w3 = n3;
    }
  };

  // LIF + stats + spike publish for layers 0..2 (acc = mm result, no bias)
  auto lif_layer = [&](int l, float acc[NB], int t) {
    const float bbx = bL[l];
    float sv = 0.f, svt = 0.f;
    float mxv = -3.402823466e38f, mnv = 3.402823466e38f;
    float mxvt = -3.402823466e38f, mnvt = 3.402823466e38f;
    float sn[NB];
    #pragma unroll
    for (int j = 0; j < NB; ++j) {
      float un = fmaf(u[l][j], 0.5f, acc[j]) + bbx;
      float vp = v[l][j];
      float vd = (vp * 0.75f) * (1.0f - s[l][j]);
      float vn = vd + un;
      float en = expf((vp - vn) / 3.0f) - 1.0f;
      float vt = 0.5f * tp[l][j] + 0.5f * en;
      float sx = (vn > vt) ? 1.0f : 0.0f;
      u[l][j] = un; v[l][j] = vn; s[l][j] = sx;
      sn[j] = sx;
      sv += vn; svt += vt;
      mxv = fmaxf(mxv, vn); mnv = fminf(mnv, vn);
      mxvt = fmaxf(mxvt, vt); mnvt = fminf(mnvt, vt);
    }
    #pragma unroll
    for (int m = 1; m < 64; m <<= 1) {
      sv += __shfl_xor(sv, m);   svt += __shfl_xor(svt, m);
      mxv = fmaxf(mxv, __shfl_xor(mxv, m));  mnv = fminf(mnv, __shfl_xor(mnv, m));
      mxvt = fmaxf(mxvt, __shfl_xor(mxvt, m)); mnvt = fminf(mnvt, __shfl_xor(mnvt, m));
    }
    __syncthreads();   // prior in_lds readers done; wred free
    if ((tid & 63) == 0) {
      int wv = tid >> 6;
      wred[wv][0] = sv;  wred[wv][1] = mxv;  wred[wv][2] = mnv;
      wred[wv][3] = svt; wred[wv][4] = mxvt; wred[wv][5] = mnvt;
    }
    *reinterpret_cast<float4*>(&in_lds[h0 * NB]) =
        make_float4(sn[0], sn[1], sn[2], sn[3]);
    __syncthreads();   // spikes + wred visible
    if (tid < 6) {
      int st = tid; float r;
      if (st == 0 || st == 3)
        r = ((wred[0][st] + wred[1][st]) + wred[2][st]) + wred[3][st];
      else if (st == 1 || st == 4)
        r = fmaxf(fmaxf(wred[0][st], wred[1][st]), fmaxf(wred[2][st], wred[3][st]));
      else
        r = fminf(fminf(wred[0][st], wred[1][st]), fminf(wred[2][st], wred[3][st]));
      pstore(&p.partials[(((size_t)(t & 1) * 4 + l) * 6 + st) * NBLK + blk], r);
    }
  };

  #pragma unroll 1
  for (int t = 0; t < TT; ++t) {
    __syncthreads();

    // ---- layer-1 pre-activation ----
    float pre[NB];
    if (p.use_p1) {
      #pragma unroll
      for (int j = 0; j < NB; ++j)
        pre[j] = p.P1[((size_t)t * BB + B0 + j) * HH + h0];
    } else {
      #pragma unroll
      for (int j = 0; j < NB; ++j)
        x_lds[tid * NB + j] = p.x[((size_t)(B0 + j) * SS + tid) * TT + t];
      __syncthreads();
      gemm(p.wt3, x_lds, pre);
    }

    // ---- stats(t-1) -> V_m, V_theta -> temporal update ----
    if (t > 0) {
      bar_wait(p.bar, t);
      {
        const int wv = tid >> 6, ln = tid & 63;
        const float* pb = p.partials + ((size_t)((t - 1) & 1) * 4 + wv) * 6 * NBLK;
        float r[6];
        #pragma unroll
        for (int st = 0; st < 6; ++st) {
          const float* q = pb + st * NBLK;
          float a0 = pload(q + ln),       a1 = pload(q + ln + 64);
          float a2 = pload(q + ln + 128), a3 = pload(q + ln + 192);
          float a4 = pload(q + ln + 256), a5 = pload(q + ln + 320);
          float a6 = pload(q + ln + 384), a7 = pload(q + ln + 448);
          float rr;
          if (st == 0 || st == 3) {
            rr = ((((((a0 + a1) + a2) + a3) + a4) + a5) + a6) + a7;
            #pragma unroll
            for (int m = 1; m < 64; m <<= 1) rr += __shfl_xor(rr, m);
          } else if (st == 1 || st == 4) {
            rr = fmaxf(fmaxf(fmaxf(a0, a1), fmaxf(a2, a3)),
                       fmaxf(fmaxf(a4, a5), fmaxf(a6, a7)));
            #pragma unroll
            for (int m = 1; m < 64; m <<= 1) rr = fmaxf(rr, __shfl_xor(rr, m));
          } else {
            rr = fminf(fminf(fminf(a0, a1), fminf(a2, a3)),
                       fminf(fminf(a4, a5), fminf(a6, a7)));
            #pragma unroll
            for (int m = 1; m < 64; m <<= 1) rr = fminf(rr, __shfl_xor(rr, m));
          }
          r[st] = rr;
        }
        if (ln == 0) {
          const float invN = (wv == 3) ? (1.0f / 4096.0f) : (1.0f / 524288.0f);
          scal[wv][0] = (r[0] * invN) - 0.2f * (r[1] - r[2]);
          scal[wv][1] = (r[3] * invN) - 0.2f * (r[4] - r[5]);
        }
      }
      __syncthreads();
      #pragma unroll
      for (int l2 = 0; l2 < 3; ++l2) {
        const float Vm = scal[l2][0], Vt = scal[l2][1];
        #pragma unroll
        for (int j = 0; j < NB; ++j) {
          float d = v[l2][j] - Vm;   // v still holds v(t-1)
          float sp = logf(1.0f + expf(d * 0.25f));
          tp[l2][j] = (0.01f * d + Vt) + sp;
        }
      }
      if (tid < 8) {
        const float Vm = scal[3][0], Vt = scal[3][1];
        float d = l4v[tid] - Vm;
        float sp = logf(1.0f + expf(d * 0.25f));
        l4t[tid] = (0.01f * d + Vt) + sp;
      }
      __syncthreads();
    }

    // ---- layer 1 LIF (+publish s1) ----
    lif_layer(0, pre, t);

    // ---- layers 2,3 ----
    {
      float acc[NB];
      gemm(p.wt3 + WLAYER, in_lds, acc);
      lif_layer(1, acc, t);
      gemm(p.wt3 + 2 * WLAYER, in_lds, acc);
      lif_layer(2, acc, t);
    }

    // ---- layer 4 (H -> 2) ----
    {
      const int g = tid >> 4, c = tid & 15;
      if (g < 8) {
        const int j4 = g >> 1, a4 = g & 1;
        float part = 0.0f;
        #pragma unroll
        for (int i = 0; i < 16; ++i) {
          int k = c + 16 * i;
          part = fmaf(in_lds[k * NB + j4], p.W4[a4 * HH + k], part);
        }
        #pragma unroll
        for (int m = 1; m < 16; m <<= 1) part += __shfl_xor(part, m);
        if (c == 0) {
          float un = fmaf(l4u[g], 0.5f, part) + p.b4[a4];
          float vp = l4v[g];
          float vd = (vp * 0.75f) * (1.0f - l4s[g]);
          float vn = vd + un;
          float en = expf((vp - vn) / 3.0f) - 1.0f;
          float vt = 0.5f * l4t[g] + 0.5f * en;
          float sx = (vn > vt) ? 1.0f : 0.0f;
          l4u[g] = un; l4v[g] = vn; l4s[g] = sx;
          l4acc[g] += sx; l4vn[g] = vn; l4vth[g] = vt;
        }
      }
    }
    __syncthreads();

    if (tid == 0) {
      float sv4 = l4vn[0], mx4 = l4vn[0], mn4 = l4vn[0];
      float st4 = l4vth[0], mxt4 = l4vth[0], mnt4 = l4vth[0];
      #pragma unroll
      for (int g2 = 1; g2 < 8; ++g2) {
        sv4 += l4vn[g2]; mx4 = fmaxf(mx4, l4vn[g2]); mn4 = fminf(mn4, l4vn[g2]);
        st4 += l4vth[g2]; mxt4 = fmaxf(mxt4, l4vth[g2]); mnt4 = fminf(mnt4, l4vth[g2]);
      }
      float* pp = p.partials + ((size_t)(t & 1) * 4 + 3) * 6 * NBLK + blk;
      pstore(pp + 0 * NBLK, sv4);  pstore(pp + 1 * NBLK, mx4);  pstore(pp + 2 * NBLK, mn4);
      pstore(pp + 3 * NBLK, st4);  pstore(pp + 4 * NBLK, mxt4); pstore(pp + 5 * NBLK, mnt4);
    }

    if (t < TT - 1) bar_arrive(p.bar, t + 1);
  }

  __syncthreads();
  if (tid < 8) {
    int j = tid >> 1, a = tid & 1;
    p.out[(size_t)(B0 + j) * AA + a] = l4acc[tid] / 50.0f;
  }
}

extern "C" void kernel_launch(void* const* d_in, const int* in_sizes, int n_in,
                              void* d_out, int out_size, void* d_ws, size_t ws_size,
                              hipStream_t stream) {
  Params p;
  p.x     = (const float*)d_in[0];
  p.fu[0] = (const float*)d_in[1];  p.fv[0] = (const float*)d_in[2];  p.fs[0] = (const float*)d_in[3];
  p.fu[1] = (const float*)d_in[4];  p.fv[1] = (const float*)d_in[5];  p.fs[1] = (const float*)d_in[6];
  p.fu[2] = (const float*)d_in[7];  p.fv[2] = (const float*)d_in[8];  p.fs[2] = (const float*)d_in[9];
  p.f4u   = (const float*)d_in[10]; p.f4v   = (const float*)d_in[11]; p.f4s   = (const float*)d_in[12];
  p.W[0]  = (const float*)d_in[13]; p.bs[0] = (const float*)d_in[14];
  p.W[1]  = (const float*)d_in[15]; p.bs[1] = (const float*)d_in[16];
  p.W[2]  = (const float*)d_in[17]; p.bs[2] = (const float*)d_in[18];
  p.W4    = (const float*)d_in[19]; p.b4    = (const float*)d_in[20];
  p.out   = (float*)d_out;

  float* ws  = (float*)d_ws;
  p.wt3      = ws;                         // 3*69632 = 208896 floats
  p.partials = ws + 208896;                // 24576 floats
  p.bar      = (unsigned*)(ws + 233472);   // pad to 64
  p.P1       = ws + 233536;                // 50*2048*256 = 26214400 floats
  size_t need = ((size_t)233536 + (size_t)TT * BB * HH) * sizeof(float);
  p.use_p1   = (ws_size >= need) ? 1 : 0;

  hipMemsetAsync((void*)p.bar, 0, 2 * sizeof(unsigned), stream);
  snn_kernel<<<dim3(NBLK), dim3(NTHR), 0, stream>>>(p);
}